// Round 1
// baseline (1694.211 us; speedup 1.0000x reference)
//
#include <hip/hip_runtime.h>

#define N_NODES 100000
#define N_EDGES 3200000
#define DIM 128
#define HID 32

// Workspace layout (floats):
//  [0, N)                      deg -> dinv (in place)
//  [N, N + N*HID)              y1 = (x@W1)*dinv[row]
//  [N + N*HID, N + 2*N*HID)    acc1 (edge scatter accumulator, layer 1)
//  [N + 2*N*HID, + N)          y2 = (h@W2)*dinv[row]
//  [.., + N)                   acc2 (edge scatter accumulator, layer 2)

__global__ void k_init(float* __restrict__ deg, float* __restrict__ acc1,
                       float* __restrict__ acc2) {
    int i = blockIdx.x * blockDim.x + threadIdx.x;
    int stride = gridDim.x * blockDim.x;
    for (int j = i; j < N_NODES; j += stride) {
        deg[j] = 1.0f;   // self loop
        acc2[j] = 0.0f;
    }
    for (int j = i; j < N_NODES * HID; j += stride) acc1[j] = 0.0f;
}

__global__ void k_count(const int* __restrict__ dst, float* __restrict__ deg) {
    int i = blockIdx.x * blockDim.x + threadIdx.x;
    int stride = gridDim.x * blockDim.x;
    for (int e = i; e < N_EDGES; e += stride) {
        atomicAdd(&deg[dst[e]], 1.0f);
    }
}

__global__ void k_rsqrt(float* __restrict__ deg) {
    int i = blockIdx.x * blockDim.x + threadIdx.x;
    if (i < N_NODES) deg[i] = rsqrtf(deg[i]);
}

// y1[v][c] = dinv[v] * sum_k x[v][k] * W1[k][c]
// 256 threads = 8 nodes x 32 cols. W1 (16KB) staged in LDS.
__launch_bounds__(256)
__global__ void k_gemm1(const float* __restrict__ x, const float* __restrict__ W1,
                        const float* __restrict__ dinv, float* __restrict__ y1) {
    __shared__ float Wl[DIM * HID];
    for (int i = threadIdx.x; i < DIM * HID; i += 256) Wl[i] = W1[i];
    __syncthreads();
    int node = blockIdx.x * 8 + (threadIdx.x >> 5);
    int col = threadIdx.x & 31;
    if (node >= N_NODES) return;
    const float4* x4 = (const float4*)(x + (size_t)node * DIM);
    float acc = 0.0f;
    #pragma unroll
    for (int k4 = 0; k4 < DIM / 4; ++k4) {
        float4 v = x4[k4];                    // broadcast across the 32 lanes of a node
        int k = k4 * 4;
        acc = fmaf(v.x, Wl[(k + 0) * HID + col], acc);   // banks 0..31: conflict-free
        acc = fmaf(v.y, Wl[(k + 1) * HID + col], acc);
        acc = fmaf(v.z, Wl[(k + 2) * HID + col], acc);
        acc = fmaf(v.w, Wl[(k + 3) * HID + col], acc);
    }
    y1[(size_t)node * HID + col] = dinv[node] * acc;
}

// 8 threads per edge; each reads a float4 of y1[src] and does 4 atomic adds into acc1[dst].
__launch_bounds__(256)
__global__ void k_scatter1(const int* __restrict__ src, const int* __restrict__ dst,
                           const float* __restrict__ y1, float* __restrict__ acc1) {
    long long tid = (long long)blockIdx.x * blockDim.x + threadIdx.x;
    if (tid >= (long long)N_EDGES * 8) return;
    int e = (int)(tid >> 3);
    int p = (int)(tid & 7);
    int u = src[e];
    int v = dst[e];
    float4 val = ((const float4*)(y1 + (size_t)u * HID))[p];
    float* base = acc1 + (size_t)v * HID + p * 4;
    atomicAdd(base + 0, val.x);
    atomicAdd(base + 1, val.y);
    atomicAdd(base + 2, val.z);
    atomicAdd(base + 3, val.w);
}

// h[v][c] = relu(dinv[v]*(acc1+y1) + b1[c]) -> d_out; y2[v] = dinv[v]*(h[v].W2)
__launch_bounds__(256)
__global__ void k_finish1(const float* __restrict__ acc1, const float* __restrict__ y1,
                          const float* __restrict__ dinv, const float* __restrict__ b1,
                          const float* __restrict__ W2, float* __restrict__ out_h,
                          float* __restrict__ y2) {
    int node = blockIdx.x * 8 + (threadIdx.x >> 5);
    int col = threadIdx.x & 31;
    if (node >= N_NODES) return;
    float di = dinv[node];
    size_t idx = (size_t)node * HID + col;
    float hval = di * (acc1[idx] + y1[idx]) + b1[col];
    hval = fmaxf(hval, 0.0f);
    out_h[idx] = hval;
    float p = hval * W2[col];
    #pragma unroll
    for (int off = 16; off > 0; off >>= 1) p += __shfl_xor(p, off);  // stays within 32-lane group
    if (col == 0) y2[node] = di * p;
}

__global__ void k_scatter2(const int* __restrict__ src, const int* __restrict__ dst,
                           const float* __restrict__ y2, float* __restrict__ acc2) {
    int i = blockIdx.x * blockDim.x + threadIdx.x;
    int stride = gridDim.x * blockDim.x;
    for (int e = i; e < N_EDGES; e += stride) {
        atomicAdd(&acc2[dst[e]], y2[src[e]]);
    }
}

__global__ void k_finish2(const float* __restrict__ acc2, const float* __restrict__ y2,
                          const float* __restrict__ dinv, const float* __restrict__ b2,
                          float* __restrict__ scores) {
    int v = blockIdx.x * blockDim.x + threadIdx.x;
    if (v < N_NODES) scores[v] = dinv[v] * (acc2[v] + y2[v]) + b2[0];
}

extern "C" void kernel_launch(void* const* d_in, const int* in_sizes, int n_in,
                              void* d_out, int out_size, void* d_ws, size_t ws_size,
                              hipStream_t stream) {
    const float* x  = (const float*)d_in[0];
    const int* ei   = (const int*)d_in[1];
    const float* W1 = (const float*)d_in[2];
    const float* b1 = (const float*)d_in[3];
    const float* W2 = (const float*)d_in[4];
    const float* b2 = (const float*)d_in[5];

    const int* src = ei;             // edge_index[0]
    const int* dst = ei + N_EDGES;   // edge_index[1]

    float* ws   = (float*)d_ws;
    float* deg  = ws;                          // N (becomes dinv)
    float* y1   = deg + N_NODES;               // N*HID
    float* acc1 = y1 + (size_t)N_NODES * HID;  // N*HID
    float* y2   = acc1 + (size_t)N_NODES * HID;// N
    float* acc2 = y2 + N_NODES;                // N

    float* out_h = (float*)d_out;                       // N*HID
    float* out_s = out_h + (size_t)N_NODES * HID;       // N

    // 1. init accumulators + deg=1
    k_init<<<2048, 256, 0, stream>>>(deg, acc1, acc2);
    // 2. in-degree count
    k_count<<<N_EDGES / 256, 256, 0, stream>>>(dst, deg);
    // 3. dinv = rsqrt(deg)
    k_rsqrt<<<(N_NODES + 255) / 256, 256, 0, stream>>>(deg);
    // 4. y1 = (x@W1) * dinv[row]
    k_gemm1<<<(N_NODES + 7) / 8, 256, 0, stream>>>(x, W1, deg, y1);
    // 5. scatter layer-1
    {
        long long total = (long long)N_EDGES * 8;
        int blocks = (int)((total + 255) / 256);
        k_scatter1<<<blocks, 256, 0, stream>>>(src, dst, y1, acc1);
    }
    // 6. h + y2
    k_finish1<<<(N_NODES + 7) / 8, 256, 0, stream>>>(acc1, y1, deg, b1, W2, out_h, y2);
    // 7. scatter layer-2
    k_scatter2<<<N_EDGES / 256, 256, 0, stream>>>(src, dst, y2, acc2);
    // 8. scores
    k_finish2<<<(N_NODES + 255) / 256, 256, 0, stream>>>(acc2, y2, deg, b2, out_s);
}

// Round 2
// 560.503 us; speedup vs baseline: 3.0227x; 3.0227x over previous
//
#include <hip/hip_runtime.h>

#define N_NODES 100000
#define N_EDGES 3200000
#define DIM 128
#define HID 32

#define SCHUNK 512
#define SNBLK ((N_NODES + SCHUNK - 1) / SCHUNK)   // 196

// Workspace layout (ints/floats, total exactly 26,800,000 B):
//  cnt    : N ints   (in-degree counts; reused as y2 float[N] after scan)
//  cursor : N ints   (exclusive prefix -> bumped by fill -> row ENDs)
//  csr    : E ints   (edge srcs sorted by dst; first SNBLK entries alias scan partials)
//  dinv   : N floats
//  y1     : N*HID floats

__global__ void k_zero(int* __restrict__ cnt) {
    int i = blockIdx.x * blockDim.x + threadIdx.x;
    if (i < N_NODES) cnt[i] = 0;
}

__global__ void k_count(const int* __restrict__ dst, int* __restrict__ cnt) {
    int e = blockIdx.x * blockDim.x + threadIdx.x;
    if (e >= N_EDGES) return;
    atomicAdd(&cnt[dst[e]], 1);
}

// block b sums cnt[b*512 .. b*512+512) -> partials[b]
__global__ void k_scanA(const int* __restrict__ cnt, int* __restrict__ partials) {
    __shared__ int s[256];
    int t = threadIdx.x;
    int base = blockIdx.x * SCHUNK;
    int a = 0;
    int i0 = base + t, i1 = base + 256 + t;
    if (i0 < N_NODES) a += cnt[i0];
    if (i1 < N_NODES) a += cnt[i1];
    s[t] = a; __syncthreads();
    for (int d = 128; d > 0; d >>= 1) {
        if (t < d) s[t] += s[t + d];
        __syncthreads();
    }
    if (t == 0) partials[blockIdx.x] = s[0];
}

// single block: exclusive-scan partials[SNBLK] in place
__global__ void k_scanB(int* __restrict__ partials) {
    __shared__ int s[256];
    int t = threadIdx.x;
    int v = (t < SNBLK) ? partials[t] : 0;
    s[t] = v; __syncthreads();
    for (int d = 1; d < 256; d <<= 1) {
        int add = (t >= d) ? s[t - d] : 0;
        __syncthreads();
        s[t] += add;
        __syncthreads();
    }
    if (t < SNBLK) partials[t] = s[t] - v;   // exclusive
}

// per-element exclusive scan within chunk + block offset -> cursor; dinv = rsqrt(deg+1)
__global__ void k_scanC(const int* __restrict__ cnt, const int* __restrict__ partials,
                        int* __restrict__ cursor, float* __restrict__ dinv) {
    __shared__ int s[256];
    int t = threadIdx.x;
    int base = blockIdx.x * SCHUNK;
    int e0 = base + 2 * t, e1 = e0 + 1;
    int c0 = (e0 < N_NODES) ? cnt[e0] : 0;
    int c1 = (e1 < N_NODES) ? cnt[e1] : 0;
    int local = c0 + c1;
    s[t] = local; __syncthreads();
    for (int d = 1; d < 256; d <<= 1) {
        int add = (t >= d) ? s[t - d] : 0;
        __syncthreads();
        s[t] += add;
        __syncthreads();
    }
    int excl = s[t] - local + partials[blockIdx.x];
    if (e0 < N_NODES) { cursor[e0] = excl;      dinv[e0] = rsqrtf((float)(c0 + 1)); }
    if (e1 < N_NODES) { cursor[e1] = excl + c0; dinv[e1] = rsqrtf((float)(c1 + 1)); }
}

// pos = bump cursor[dst]; csr[pos] = src. After this, cursor[v] == row END of v.
__global__ void k_fill(const int* __restrict__ src, const int* __restrict__ dst,
                       int* __restrict__ cursor, int* __restrict__ csr) {
    int e = blockIdx.x * blockDim.x + threadIdx.x;
    if (e >= N_EDGES) return;
    int pos = atomicAdd(&cursor[dst[e]], 1);
    csr[pos] = src[e];
}

// y1[v][c] = dinv[v] * sum_k x[v][k] * W1[k][c]; 8 nodes x 32 cols per block
__launch_bounds__(256)
__global__ void k_gemm1(const float* __restrict__ x, const float* __restrict__ W1,
                        const float* __restrict__ dinv, float* __restrict__ y1) {
    __shared__ float Wl[DIM * HID];
    for (int i = threadIdx.x; i < DIM * HID; i += 256) Wl[i] = W1[i];
    __syncthreads();
    int node = blockIdx.x * 8 + (threadIdx.x >> 5);
    int col = threadIdx.x & 31;
    if (node >= N_NODES) return;
    const float4* x4 = (const float4*)(x + (size_t)node * DIM);
    float acc = 0.0f;
    #pragma unroll
    for (int k4 = 0; k4 < DIM / 4; ++k4) {
        float4 v = x4[k4];
        int k = k4 * 4;
        acc = fmaf(v.x, Wl[(k + 0) * HID + col], acc);
        acc = fmaf(v.y, Wl[(k + 1) * HID + col], acc);
        acc = fmaf(v.z, Wl[(k + 2) * HID + col], acc);
        acc = fmaf(v.w, Wl[(k + 3) * HID + col], acc);
    }
    y1[(size_t)node * HID + col] = dinv[node] * acc;
}

// Gather layer 1 + fused epilogue. 32-lane group per node, lane = feature col.
// out_h = relu(dinv[v]*(sum_nbr y1[u] + y1[v]) + b1); y2[v] = dinv[v]*(h . W2)
__launch_bounds__(256)
__global__ void k_gather1(const int* __restrict__ cursor, const int* __restrict__ csr,
                          const float* __restrict__ y1, const float* __restrict__ dinv,
                          const float* __restrict__ b1, const float* __restrict__ W2,
                          float* __restrict__ out_h, float* __restrict__ y2) {
    int v = blockIdx.x * 8 + (threadIdx.x >> 5);
    int col = threadIdx.x & 31;
    if (v >= N_NODES) return;
    int start = (v == 0) ? 0 : cursor[v - 1];
    int end = cursor[v];
    float a0 = 0.f, a1 = 0.f, a2 = 0.f, a3 = 0.f;
    int j = start;
    for (; j + 4 <= end; j += 4) {          // 4 independent loads in flight
        int u0 = csr[j + 0], u1 = csr[j + 1], u2 = csr[j + 2], u3 = csr[j + 3];
        a0 += y1[(size_t)u0 * HID + col];
        a1 += y1[(size_t)u1 * HID + col];
        a2 += y1[(size_t)u2 * HID + col];
        a3 += y1[(size_t)u3 * HID + col];
    }
    for (; j < end; ++j) a0 += y1[(size_t)csr[j] * HID + col];
    float acc = (a0 + a1) + (a2 + a3);
    acc += y1[(size_t)v * HID + col];        // self loop
    float di = dinv[v];
    float h = fmaxf(fmaf(di, acc, b1[col]), 0.f);
    out_h[(size_t)v * HID + col] = h;
    float p = h * W2[col];
    #pragma unroll
    for (int off = 16; off > 0; off >>= 1) p += __shfl_xor(p, off);  // within 32-group
    if (col == 0) y2[v] = di * p;
}

// Gather layer 2: 32 lanes over neighbors summing y2[src]
__launch_bounds__(256)
__global__ void k_gather2(const int* __restrict__ cursor, const int* __restrict__ csr,
                          const float* __restrict__ y2, const float* __restrict__ dinv,
                          const float* __restrict__ b2, float* __restrict__ scores) {
    int v = blockIdx.x * 8 + (threadIdx.x >> 5);
    int lane = threadIdx.x & 31;
    if (v >= N_NODES) return;
    int start = (v == 0) ? 0 : cursor[v - 1];
    int end = cursor[v];
    float acc = 0.f;
    for (int j = start + lane; j < end; j += 32) acc += y2[csr[j]];
    #pragma unroll
    for (int off = 16; off > 0; off >>= 1) acc += __shfl_xor(acc, off);
    if (lane == 0) scores[v] = dinv[v] * (acc + y2[v]) + b2[0];
}

extern "C" void kernel_launch(void* const* d_in, const int* in_sizes, int n_in,
                              void* d_out, int out_size, void* d_ws, size_t ws_size,
                              hipStream_t stream) {
    const float* x  = (const float*)d_in[0];
    const int* ei   = (const int*)d_in[1];
    const float* W1 = (const float*)d_in[2];
    const float* b1 = (const float*)d_in[3];
    const float* W2 = (const float*)d_in[4];
    const float* b2 = (const float*)d_in[5];

    const int* src = ei;             // edge_index[0]
    const int* dst = ei + N_EDGES;   // edge_index[1]

    int* cnt    = (int*)d_ws;                    // N ints (later reused as y2)
    int* cursor = cnt + N_NODES;                 // N ints
    int* csr    = cursor + N_NODES;              // E ints
    int* partials = csr;                         // aliases csr head; disjoint in time
    float* dinv = (float*)(csr + N_EDGES);       // N floats
    float* y1   = dinv + N_NODES;                // N*HID floats
    float* y2   = (float*)cnt;                   // reuse after scan

    float* out_h = (float*)d_out;                       // N*HID
    float* out_s = out_h + (size_t)N_NODES * HID;       // N

    k_zero <<<(N_NODES + 255) / 256, 256, 0, stream>>>(cnt);
    k_count<<<N_EDGES / 256, 256, 0, stream>>>(dst, cnt);
    k_scanA<<<SNBLK, 256, 0, stream>>>(cnt, partials);
    k_scanB<<<1, 256, 0, stream>>>(partials);
    k_scanC<<<SNBLK, 256, 0, stream>>>(cnt, partials, cursor, dinv);
    k_gemm1<<<(N_NODES + 7) / 8, 256, 0, stream>>>(x, W1, dinv, y1);
    k_fill <<<N_EDGES / 256, 256, 0, stream>>>(src, dst, cursor, csr);
    k_gather1<<<(N_NODES + 7) / 8, 256, 0, stream>>>(cursor, csr, y1, dinv, b1, W2, out_h, y2);
    k_gather2<<<(N_NODES + 7) / 8, 256, 0, stream>>>(cursor, csr, y2, dinv, b2, out_s);
}